// Round 6
// baseline (24.911 us; speedup 1.0000x reference)
//
#include <hip/hip_runtime.h>

// y[b,q] = sum_{d,f} amp[b,d,f] * sin(x_q[b,q,d] * freq[b,d,f])
//
// R6: two-kernel table scheme.
//  K1 (build): tables g_{b,d}(x) = sum_f amp*sin(freq*x), 512 pts over [-8,8]
//     (delta=1/32, linear interp — absmax 0.5 validated in R5), built ONCE
//     into d_ws via the Chebyshev recurrence s_{k+1}=w*s_k-s_{k-1}.
//     4 MB total, ~1 us, no redundancy.
//  K2 (lookup): block = (b, 16-d slice, 512-q slice). 32 KB LDS table ->
//     4 blocks/CU -> 8 waves/SIMD (R5 died at 2). Each thread: 1 q, 64 B
//     contiguous x-load, 16 interp lookups, one atomicAdd into zeroed out.
#define ND 64
#define NF 16
#define TPTS 512
#define SEGP 16
#define DELTA 0.03125f
#define XSCALE 32.0f
#define XBIAS 256.0f   // (x+8)*32
#define IMAX 510.99f   // i+1 <= 511
#define DSL 16
#define QSL 512

// ---------------- K1: build all tables into ws ----------------
__global__ __launch_bounds__(256) void sinreg_build(
    const float* __restrict__ z, float* __restrict__ tblg, int B) {
  const int t = blockIdx.x * 256 + threadIdx.x;   // (b, d, seg)
  const int b   = t >> 11;
  const int d   = (t >> 5) & (ND - 1);
  const int seg = t & 31;
  const int k0  = seg * SEGP;
  const float xs = -8.0f + k0 * DELTA;

  const float* __restrict__ zb = z + (size_t)b * (2 * ND * NF);
  const float* __restrict__ ap = zb + d * NF;            // amp[d][f]
  const float* __restrict__ fp = zb + ND * NF + d * NF;  // freq[d][f]
  constexpr float INV2PI = 0.15915494309189535f;

  float g[SEGP];
  #pragma unroll
  for (int k = 0; k < SEGP; ++k) g[k] = 0.f;

  #pragma unroll
  for (int f = 0; f < NF; ++f) {
    const float fv = fp[f], av = ap[f];
    float s0 = __builtin_amdgcn_sinf(__builtin_amdgcn_fractf(fv * xs * INV2PI));
    float s1 = __builtin_amdgcn_sinf(
        __builtin_amdgcn_fractf(fv * (xs + DELTA) * INV2PI));
    const float th2 = (fv * DELTA) * (fv * DELTA);
    const float w = fmaf(th2, fmaf(th2, 0.0833333333f, -1.0f), 2.0f);  // 2cos
    g[0] = fmaf(av, s0, g[0]);
    g[1] = fmaf(av, s1, g[1]);
    #pragma unroll
    for (int k = 2; k < SEGP; ++k) {
      const float s2 = fmaf(w, s1, -s0);
      g[k] = fmaf(av, s2, g[k]);
      s0 = s1; s1 = s2;
    }
  }
  float4* __restrict__ dst =
      reinterpret_cast<float4*>(tblg + ((size_t)(b * ND + d) * TPTS) + k0);
  #pragma unroll
  for (int j = 0; j < 4; ++j)
    dst[j] = make_float4(g[4 * j], g[4 * j + 1], g[4 * j + 2], g[4 * j + 3]);
}

// ---------------- K2: lookup ----------------
__global__ __launch_bounds__(512, 4) void sinreg_lookup(
    const float* __restrict__ tblg,
    const float* __restrict__ xq,
    float* __restrict__ out,
    int B, int Q) {
  __shared__ float s_tbl[DSL * TPTS];  // 32 KB

  const int b   = blockIdx.y;
  const int dsl = blockIdx.x & 3;   // 16-d slice
  const int qsl = blockIdx.x >> 2;  // 512-q slice
  const int d0  = dsl * DSL;
  const int tid = threadIdx.x;

  // stage table (32 KB, L2-hot after first block touches it)
  {
    const float4* __restrict__ src =
        reinterpret_cast<const float4*>(tblg + (size_t)(b * ND + d0) * TPTS);
    float4* __restrict__ dst = reinterpret_cast<float4*>(s_tbl);
    #pragma unroll
    for (int i = 0; i < 4; ++i) dst[tid + i * 512] = src[tid + i * 512];
  }
  __syncthreads();

  const int q = qsl * QSL + tid;
  const float4* __restrict__ xp =
      reinterpret_cast<const float4*>(xq + ((size_t)b * Q + q) * ND + d0);
  const float4 X0 = xp[0], X1 = xp[1], X2 = xp[2], X3 = xp[3];
  const float xv[16] = {X0.x, X0.y, X0.z, X0.w, X1.x, X1.y, X1.z, X1.w,
                        X2.x, X2.y, X2.z, X2.w, X3.x, X3.y, X3.z, X3.w};

  float a0 = 0.f, a1 = 0.f;
  #pragma unroll
  for (int d = 0; d < DSL; d += 2) {
    {
      float t = fmaf(xv[d], XSCALE, XBIAS);
      t = fminf(fmaxf(t, 0.0f), IMAX);
      const unsigned i = (unsigned)t;
      const float u = t - (float)i;
      const float t0 = s_tbl[d * TPTS + i];
      const float t1 = s_tbl[d * TPTS + i + 1];
      a0 += fmaf(u, t1 - t0, t0);
    }
    {
      float t = fmaf(xv[d + 1], XSCALE, XBIAS);
      t = fminf(fmaxf(t, 0.0f), IMAX);
      const unsigned i = (unsigned)t;
      const float u = t - (float)i;
      const float t0 = s_tbl[(d + 1) * TPTS + i];
      const float t1 = s_tbl[(d + 1) * TPTS + i + 1];
      a1 += fmaf(u, t1 - t0, t0);
    }
  }
  atomicAdd(&out[(size_t)b * Q + q], a0 + a1);
}

// ---------------- fallback (direct v_sin, R3-validated) ----------------
__global__ __launch_bounds__(256, 4) void sinreg_direct(
    const float* __restrict__ z, const float* __restrict__ xq,
    float* __restrict__ out, int B, int Q) {
  __shared__ float s_part[4][64];
  const int b = blockIdx.y;
  const int lane = threadIdx.x & 63;
  const int wv = __builtin_amdgcn_readfirstlane((int)(threadIdx.x >> 6));
  const int q = blockIdx.x * 64 + lane;
  const float* __restrict__ zb  = z + (size_t)b * (2 * ND * NF);
  const float* __restrict__ amp = zb + (16 * wv) * NF;
  const float* __restrict__ frq = zb + ND * NF + (16 * wv) * NF;
  const float4* __restrict__ xrow =
      reinterpret_cast<const float4*>(xq + ((size_t)b * Q + q) * ND + 16 * wv);
  float4 xv0 = xrow[0], xv1 = xrow[1], xv2 = xrow[2], xv3 = xrow[3];
  constexpr float INV2PI = 0.15915494309189535f;
  const float xs[16] = {
      xv0.x * INV2PI, xv0.y * INV2PI, xv0.z * INV2PI, xv0.w * INV2PI,
      xv1.x * INV2PI, xv1.y * INV2PI, xv1.z * INV2PI, xv1.w * INV2PI,
      xv2.x * INV2PI, xv2.y * INV2PI, xv2.z * INV2PI, xv2.w * INV2PI,
      xv3.x * INV2PI, xv3.y * INV2PI, xv3.z * INV2PI, xv3.w * INV2PI};
  float acc0 = 0.f, acc1 = 0.f, acc2 = 0.f, acc3 = 0.f;
  #pragma unroll
  for (int dd = 0; dd < 16; ++dd) {
    const float xsd = xs[dd];
    #pragma unroll
    for (int f = 0; f < NF; f += 4) {
      acc0 = fmaf(__builtin_amdgcn_sinf(__builtin_amdgcn_fractf(xsd * frq[dd * NF + f + 0])), amp[dd * NF + f + 0], acc0);
      acc1 = fmaf(__builtin_amdgcn_sinf(__builtin_amdgcn_fractf(xsd * frq[dd * NF + f + 1])), amp[dd * NF + f + 1], acc1);
      acc2 = fmaf(__builtin_amdgcn_sinf(__builtin_amdgcn_fractf(xsd * frq[dd * NF + f + 2])), amp[dd * NF + f + 2], acc2);
      acc3 = fmaf(__builtin_amdgcn_sinf(__builtin_amdgcn_fractf(xsd * frq[dd * NF + f + 3])), amp[dd * NF + f + 3], acc3);
    }
  }
  s_part[wv][lane] = (acc0 + acc1) + (acc2 + acc3);
  __syncthreads();
  if (threadIdx.x < 64) {
    float r = (s_part[0][lane] + s_part[1][lane]) + (s_part[2][lane] + s_part[3][lane]);
    out[(size_t)b * Q + (size_t)blockIdx.x * 64 + lane] = r;
  }
}

extern "C" void kernel_launch(void* const* d_in, const int* in_sizes, int n_in,
                              void* d_out, int out_size, void* d_ws, size_t ws_size,
                              hipStream_t stream) {
  const float* z  = (const float*)d_in[0];
  const float* xq = (const float*)d_in[1];
  float* out = (float*)d_out;

  const int B = in_sizes[0] / (2 * ND * NF);  // 32
  const int Q = in_sizes[1] / (B * ND);       // 4096

  const size_t tbl_bytes = (size_t)B * ND * TPTS * sizeof(float);  // 4 MB
  if (ws_size < tbl_bytes) {  // fallback: direct evaluation (R3, validated)
    dim3 grid(Q / 64, B);
    sinreg_direct<<<grid, 256, 0, stream>>>(z, xq, out, B, Q);
    return;
  }

  float* tblg = (float*)d_ws;

  // K1: build all (b,d) tables once. threads = B*ND*32 = 65536
  sinreg_build<<<dim3((B * ND * 32) / 256), 256, 0, stream>>>(z, tblg, B);

  // out accumulates via atomicAdd from 4 d-slice blocks -> zero it
  hipMemsetAsync(d_out, 0, (size_t)out_size * sizeof(float), stream);

  // K2: (4 dsl x 8 qsl) x B = 1024 blocks, 512 thr, 32 KB LDS
  dim3 grid(4 * (Q / QSL), B);
  sinreg_lookup<<<grid, 512, 0, stream>>>(tblg, xq, out, B, Q);
}